// Round 4
// baseline (929.301 us; speedup 1.0000x reference)
//
#include <hip/hip_runtime.h>
#include <stdint.h>

#define Bsz 4
#define Lseq 4096
#define Dm 1024
#define Hh 16
#define Wc 256
#define FFd 4096
#define NC 16
#define NTOK (Bsz * Lseq)   // 16384

typedef unsigned short u16;

__device__ __forceinline__ float bf2f(u16 u) {
  union { unsigned int i; float f; } v; v.i = ((unsigned int)u) << 16; return v.f;
}
__device__ __forceinline__ u16 f2bf(float f) {
  union { float f; unsigned int i; } v; v.f = f;
  unsigned int r = v.i + 0x7fffu + ((v.i >> 16) & 1u);
  return (u16)(r >> 16);
}
__device__ __forceinline__ unsigned int pack2bf(float a, float b) {
  union { float f; unsigned int u; } x, y; x.f = a; y.f = b;
  return ((x.u + 0x8000u) >> 16) | ((y.u + 0x8000u) & 0xffff0000u);
}

// ---------------- dtype convert: f32 -> bf16 (elementwise) ----------------
__global__ void cvt_f32_bf16(const float* __restrict__ in, u16* __restrict__ out, long n) {
  long i = ((long)blockIdx.x * blockDim.x + threadIdx.x) * 4;
  if (i >= n) return;
  float4 v = *(const float4*)(in + i);
  u16 o[4] = { f2bf(v.x), f2bf(v.y), f2bf(v.z), f2bf(v.w) };
  *(uint2*)(out + i) = *(const uint2*)o;
}

// ---------------- transpose f32 [R,C] -> bf16 [C,R] ----------------
__global__ void transpose_f32_bf16(const float* __restrict__ in, u16* __restrict__ out,
                                   int R, int C) {
  __shared__ float tile[32][33];
  int tx = threadIdx.x & 31, ty = threadIdx.x >> 5;       // 32 x 8
  int r0 = blockIdx.y * 32, c0 = blockIdx.x * 32;
#pragma unroll
  for (int k = 0; k < 4; ++k)
    tile[ty + 8 * k][tx] = in[(size_t)(r0 + ty + 8 * k) * C + c0 + tx];
  __syncthreads();
#pragma unroll
  for (int k = 0; k < 4; ++k)
    out[(size_t)(c0 + ty + 8 * k) * R + r0 + tx] = f2bf(tile[tx][ty + 8 * k]);
}

// ---------------- GEMM: C[M,N] = A[M,K](bf16, row stride lda) * B[N,K](bf16)^T + bias ----
typedef __attribute__((ext_vector_type(8))) short s16x8;
typedef __attribute__((ext_vector_type(4))) float fx4;
typedef __attribute__((address_space(1))) unsigned int as1u;
typedef __attribute__((address_space(3))) unsigned int as3u;

__device__ __forceinline__ void gll16(const void* g, void* l) {
  __builtin_amdgcn_global_load_lds((as1u*)g, (as3u*)l, 16, 0, 0);
}

template <int RELU, int OUTBF16>
__global__ __launch_bounds__(256) void gemm_bt(const u16* A, int lda,
                                               const u16* Bm,
                                               const float* __restrict__ bias,
                                               void* Cp,
                                               int M, int N, int K) {
  __shared__ __attribute__((aligned(16))) u16 As[128 * 32];
  __shared__ __attribute__((aligned(16))) u16 Bs[128 * 32];
  int tid = threadIdx.x;
  int lane = tid & 63, wid = tid >> 6;

  // XCD-partition swizzle: xcd = flat % 8 on MI355X. Partition row-blocks by
  // mb % 8 == xcd (each A-strip fetched by exactly one XCD's L2), column-outer
  // within an XCD (16 consecutive same-XCD blocks share one B-strip).
  int NB = gridDim.x, MB = gridDim.y;
  int flat = blockIdx.y * NB + blockIdx.x;
  int mb, nb;
  if ((MB & 7) == 0) {
    int xcd = flat & 7;
    int j = flat >> 3;
    int rpx = MB >> 3;                 // row-blocks per XCD
    nb = j / rpx;
    int rowin = j - nb * rpx;
    mb = (rowin << 3) | xcd;
  } else {
    mb = blockIdx.y; nb = blockIdx.x;
  }
  int m0 = mb * 128, n0 = nb * 128;
  int wm = (wid >> 1) * 64, wn = (wid & 1) * 64;
  int lm = lane & 15, quad = lane >> 4;

  fx4 acc[4][4] = {};

  const u16* Ag = A + (size_t)m0 * lda;
  const u16* Bg = Bm + (size_t)n0 * K;

  for (int k0 = 0; k0 < K; k0 += 32) {
#pragma unroll
    for (int it = 0; it < 2; ++it) {
      int sb = wid * 64 + it * 256;   // wave-uniform seg base
      int s = sb + lane;
      int row = s >> 2, ks = s & 3;
      gll16(Ag + (size_t)row * lda + k0 + ks * 8, (char*)As + (size_t)sb * 16);
      gll16(Bg + (size_t)row * K + k0 + ks * 8, (char*)Bs + (size_t)sb * 16);
    }
    __syncthreads();
    s16x8 af[4], bfr[4];
#pragma unroll
    for (int t = 0; t < 4; ++t) {
      af[t]  = *(const s16x8*)(As + (wm + t * 16 + lm) * 32 + quad * 8);
      bfr[t] = *(const s16x8*)(Bs + (wn + t * 16 + lm) * 32 + quad * 8);
    }
#pragma unroll
    for (int mt = 0; mt < 4; ++mt)
#pragma unroll
      for (int nt = 0; nt < 4; ++nt)
        acc[mt][nt] = __builtin_amdgcn_mfma_f32_16x16x32_bf16(af[mt], bfr[nt], acc[mt][nt], 0, 0, 0);
    __syncthreads();
  }

  float* Cf = (float*)Cp;
  u16* Ch = (u16*)Cp;
#pragma unroll
  for (int mt = 0; mt < 4; ++mt) {
#pragma unroll
    for (int nt = 0; nt < 4; ++nt) {
      int col = n0 + wn + nt * 16 + lm;
      float bv = bias[col];
#pragma unroll
      for (int r = 0; r < 4; ++r) {
        int rowg = m0 + wm + mt * 16 + quad * 4 + r;
        float v = acc[mt][nt][r] + bv;
        if (RELU) v = v > 0.f ? v : 0.f;
        if (OUTBF16) Ch[(size_t)rowg * N + col] = f2bf(v);
        else         Cf[(size_t)rowg * N + col] = v;
      }
    }
  }
}

// ---------------- MFMA flash attention ----------------
#define PADK 72
#define PADV 136
#define PADP 40
#define PADO 72

__global__ __launch_bounds__(256, 2) void attn_mfma(u16* qkv) {
  __shared__ __attribute__((aligned(16))) u16 lds[38400];   // 76.8 KB
  u16* Klds  = lds;                    // 128 x PADK = 9216
  u16* Vtlds = lds + 9216;             // 64 x PADV  = 8704

  int bid = blockIdx.x;
  int h = bid & (Hh - 1);
  int c = (bid >> 4) & (NC - 1);
  int b = bid >> 8;
  int tid = threadIdx.x, lane = tid & 63, w = tid >> 6;
  int lm = lane & 15, quad = lane >> 4;
  u16* Pw = lds + 17920 + w * 5120;

  size_t rowbase = (size_t)b * Lseq;

  s16x8 qf[4][2];
#pragma unroll
  for (int nt = 0; nt < 4; ++nt)
#pragma unroll
    for (int ks = 0; ks < 2; ++ks) {
      int qtok = c * Wc + w * 64 + nt * 16 + lm;
      qf[nt][ks] = *(const s16x8*)(qkv + (rowbase + qtok) * 3072 + h * 64 + ks * 32 + quad * 8);
    }

  fx4 acc_o[4][4] = {};
  float lsum[4] = {0.f, 0.f, 0.f, 0.f};

  int nph = (c > 0) ? 4 : 2;
  int t0  = (c > 0) ? (c - 1) * Wc : 0;

  for (int ph = 0; ph < nph; ++ph) {
    int kt0 = t0 + ph * 128;
    __syncthreads();

#pragma unroll
    for (int it = 0; it < 4; ++it) {
      int s = tid + it * 256;
      int row = s >> 3, off = (s & 7) * 8;
      uint4 kv = *(const uint4*)(qkv + (rowbase + kt0 + row) * 3072 + 1024 + h * 64 + off);
      *(uint4*)(Klds + row * PADK + off) = kv;
    }
    {
      int d = lane;
      int kb = w * 32;
      u16 tmp[32];
#pragma unroll
      for (int i = 0; i < 32; ++i)
        tmp[i] = qkv[(rowbase + kt0 + kb + i) * 3072 + 2048 + h * 64 + d];
#pragma unroll
      for (int i = 0; i < 4; ++i)
        *(uint4*)(Vtlds + d * PADV + kb + i * 8) = *(const uint4*)(tmp + i * 8);
    }
    __syncthreads();

#pragma unroll
    for (int kt = 0; kt < 4; ++kt) {
      u16* Pb = Pw + (kt & 1) * 2560;
      fx4 sa[2][4] = {};
#pragma unroll
      for (int ks = 0; ks < 2; ++ks) {
        s16x8 kf0 = *(const s16x8*)(Klds + (kt * 32 + lm) * PADK + ks * 32 + quad * 8);
        s16x8 kf1 = *(const s16x8*)(Klds + (kt * 32 + 16 + lm) * PADK + ks * 32 + quad * 8);
#pragma unroll
        for (int nt = 0; nt < 4; ++nt) {
          sa[0][nt] = __builtin_amdgcn_mfma_f32_16x16x32_bf16(kf0, qf[nt][ks], sa[0][nt], 0, 0, 0);
          sa[1][nt] = __builtin_amdgcn_mfma_f32_16x16x32_bf16(kf1, qf[nt][ks], sa[1][nt], 0, 0, 0);
        }
      }
#pragma unroll
      for (int mt = 0; mt < 2; ++mt)
#pragma unroll
        for (int nt = 0; nt < 4; ++nt) {
          float e0 = __expf(sa[mt][nt][0] * 0.125f);
          float e1 = __expf(sa[mt][nt][1] * 0.125f);
          float e2 = __expf(sa[mt][nt][2] * 0.125f);
          float e3 = __expf(sa[mt][nt][3] * 0.125f);
          lsum[nt] += (e0 + e1) + (e2 + e3);
          uint2 pk; pk.x = pack2bf(e0, e1); pk.y = pack2bf(e2, e3);
          *(uint2*)(Pb + (nt * 16 + lm) * PADP + mt * 16 + quad * 4) = pk;
        }
#pragma unroll
      for (int mt = 0; mt < 4; ++mt) {
        s16x8 vf = *(const s16x8*)(Vtlds + (mt * 16 + lm) * PADV + kt * 32 + quad * 8);
#pragma unroll
        for (int nt = 0; nt < 4; ++nt) {
          s16x8 pf = *(const s16x8*)(Pb + (nt * 16 + lm) * PADP + quad * 8);
          acc_o[mt][nt] = __builtin_amdgcn_mfma_f32_16x16x32_bf16(vf, pf, acc_o[mt][nt], 0, 0, 0);
        }
      }
    }
  }

#pragma unroll
  for (int nt = 0; nt < 4; ++nt) {
    float v = lsum[nt];
    v += __shfl_xor(v, 16, 64);
    v += __shfl_xor(v, 32, 64);
    lsum[nt] = 1.f / v;
  }

  __syncthreads();
  u16* Obuf = lds;
#pragma unroll
  for (int mt = 0; mt < 4; ++mt)
#pragma unroll
    for (int nt = 0; nt < 4; ++nt) {
      float inv = lsum[nt];
      uint2 pk;
      pk.x = pack2bf(acc_o[mt][nt][0] * inv, acc_o[mt][nt][1] * inv);
      pk.y = pack2bf(acc_o[mt][nt][2] * inv, acc_o[mt][nt][3] * inv);
      int q = nt * 16 + lm;
      *(uint2*)(Obuf + (w * 64 + q) * PADO + mt * 16 + quad * 4) = pk;
    }
  __syncthreads();
#pragma unroll
  for (int it = 0; it < 8; ++it) {
    int s = tid + it * 256;
    int row = s >> 3, chunk = s & 7;
    uint4 v = *(const uint4*)(Obuf + row * PADO + chunk * 8);
    *(uint4*)(qkv + (rowbase + c * Wc + row) * 3072 + h * 64 + chunk * 8) = v;
  }
}

// ---------------- layernorm variants ----------------
__device__ __forceinline__ void ln_core(float sx, float sy, float sz, float sw,
                                        const float* gamma, const float* beta, int tid,
                                        float* red, float4* outv) {
  float part = sx + sy + sz + sw;
#pragma unroll
  for (int off = 32; off > 0; off >>= 1) part += __shfl_down(part, off, 64);
  if ((tid & 63) == 0) red[tid >> 6] = part;
  __syncthreads();
  float mean = (red[0] + red[1] + red[2] + red[3]) * (1.f / 1024.f);
  __syncthreads();

  float dx = sx - mean, dy = sy - mean, dz = sz - mean, dw = sw - mean;
  float sq = dx * dx + dy * dy + dz * dz + dw * dw;
#pragma unroll
  for (int off = 32; off > 0; off >>= 1) sq += __shfl_down(sq, off, 64);
  if ((tid & 63) == 0) red[tid >> 6] = sq;
  __syncthreads();
  float var = (red[0] + red[1] + red[2] + red[3]) * (1.f / 1024.f);
  float rs = rsqrtf(var + 1e-6f);

  float4 g = *(const float4*)(gamma + tid * 4);
  float4 be = *(const float4*)(beta + tid * 4);
  outv->x = g.x * dx * rs + be.x;
  outv->y = g.y * dy * rs + be.y;
  outv->z = g.z * dz * rs + be.z;
  outv->w = g.w * dw * rs + be.w;
}

__global__ __launch_bounds__(256) void ln1_kernel(const float* __restrict__ r,
                                                  const float* __restrict__ dl,
                                                  const float* __restrict__ gamma,
                                                  const float* __restrict__ beta,
                                                  u16* __restrict__ outh) {
  __shared__ float red[4];
  int row = blockIdx.x, tid = threadIdx.x;
  size_t base = (size_t)row * Dm;
  float4 rv = *(const float4*)(r + base + tid * 4);
  float4 dv = *(const float4*)(dl + base + tid * 4);
  float4 o;
  ln_core(rv.x + dv.x, rv.y + dv.y, rv.z + dv.z, rv.w + dv.w, gamma, beta, tid, red, &o);
  u16 u[4] = { f2bf(o.x), f2bf(o.y), f2bf(o.z), f2bf(o.w) };
  *(uint2*)(outh + base + tid * 4) = *(const uint2*)u;
}

__global__ __launch_bounds__(256) void ln2_kernel(const u16* __restrict__ r,
                                                  const float* dl,
                                                  const float* __restrict__ gamma,
                                                  const float* __restrict__ beta,
                                                  float* outf) {
  __shared__ float red[4];
  int row = blockIdx.x, tid = threadIdx.x;
  size_t base = (size_t)row * Dm;
  uint2 ru = *(const uint2*)(r + base + tid * 4);
  const u16* pu = (const u16*)&ru;
  float4 dv = *(const float4*)(dl + base + tid * 4);
  float4 o;
  ln_core(bf2f(pu[0]) + dv.x, bf2f(pu[1]) + dv.y, bf2f(pu[2]) + dv.z, bf2f(pu[3]) + dv.w,
          gamma, beta, tid, red, &o);
  *(float4*)(outf + base + tid * 4) = o;
}

// ---------------- launch ----------------
extern "C" void kernel_launch(void* const* d_in, const int* in_sizes, int n_in,
                              void* d_out, int out_size, void* d_ws, size_t ws_size,
                              hipStream_t stream) {
  const float* x         = (const float*)d_in[0];
  const float* in_proj_w = (const float*)d_in[1];
  const float* in_proj_b = (const float*)d_in[2];
  const float* out_w     = (const float*)d_in[3];
  const float* out_b     = (const float*)d_in[4];
  const float* gamma1    = (const float*)d_in[5];
  const float* beta1     = (const float*)d_in[6];
  const float* w1        = (const float*)d_in[7];
  const float* bf1       = (const float*)d_in[8];
  const float* w2        = (const float*)d_in[9];
  const float* bf2       = (const float*)d_in[10];
  const float* gamma2    = (const float*)d_in[11];
  const float* beta2     = (const float*)d_in[12];
  float* out = (float*)d_out;

  char* ws = (char*)d_ws;
  size_t off = 0;
  auto alloc = [&](size_t bytes) -> char* {
    char* p = ws + off;
    off += (bytes + 255) & ~(size_t)255;
    return p;
  };
  u16* wqkvh = (u16*)alloc((size_t)3 * Dm * Dm * 2);
  u16* owh   = (u16*)alloc((size_t)Dm * Dm * 2);
  u16* w1th  = (u16*)alloc((size_t)FFd * Dm * 2);
  u16* w2th  = (u16*)alloc((size_t)Dm * FFd * 2);
  u16* big   = (u16*)alloc((size_t)NTOK * FFd * 2);
  u16* x1h   = (u16*)alloc((size_t)NTOK * Dm * 2);
  u16* qkvh = big;
  u16* hh   = big;
  u16* xh   = (u16*)d_out;
  float* attnf = out;
  float* y2f   = out;

  cvt_f32_bf16<<<(long)NTOK * Dm / 1024, 256, 0, stream>>>(x, xh, (long)NTOK * Dm);
  cvt_f32_bf16<<<(long)3 * Dm * Dm / 1024, 256, 0, stream>>>(in_proj_w, wqkvh, (long)3 * Dm * Dm);
  cvt_f32_bf16<<<(long)Dm * Dm / 1024, 256, 0, stream>>>(out_w, owh, (long)Dm * Dm);
  transpose_f32_bf16<<<dim3(FFd / 32, Dm / 32), 256, 0, stream>>>(w1, w1th, Dm, FFd);
  transpose_f32_bf16<<<dim3(Dm / 32, FFd / 32), 256, 0, stream>>>(w2, w2th, FFd, Dm);

  gemm_bt<0, 1><<<dim3(3 * Dm / 128, NTOK / 128), 256, 0, stream>>>(
      xh, Dm, wqkvh, in_proj_b, qkvh, NTOK, 3 * Dm, Dm);

  attn_mfma<<<Bsz * NC * Hh, 256, 0, stream>>>(qkvh);

  gemm_bt<0, 0><<<dim3(Dm / 128, NTOK / 128), 256, 0, stream>>>(
      qkvh, 3 * Dm, owh, out_b, attnf, NTOK, Dm, Dm);

  ln1_kernel<<<NTOK, 256, 0, stream>>>(x, attnf, gamma1, beta1, x1h);

  gemm_bt<1, 1><<<dim3(FFd / 128, NTOK / 128), 256, 0, stream>>>(
      x1h, Dm, w1th, bf1, hh, NTOK, FFd, Dm);

  gemm_bt<0, 0><<<dim3(Dm / 128, NTOK / 128), 256, 0, stream>>>(
      hh, FFd, w2th, bf2, y2f, NTOK, Dm, FFd);

  ln2_kernel<<<NTOK, 256, 0, stream>>>(x1h, y2f, gamma2, beta2, out);
}

// Round 5
// 876.606 us; speedup vs baseline: 1.0601x; 1.0601x over previous
//
#include <hip/hip_runtime.h>
#include <stdint.h>

#define Bsz 4
#define Lseq 4096
#define Dm 1024
#define Hh 16
#define Wc 256
#define FFd 4096
#define NC 16
#define NTOK (Bsz * Lseq)   // 16384

typedef unsigned short u16;

__device__ __forceinline__ float bf2f(u16 u) {
  union { unsigned int i; float f; } v; v.i = ((unsigned int)u) << 16; return v.f;
}
__device__ __forceinline__ u16 f2bf(float f) {
  union { float f; unsigned int i; } v; v.f = f;
  unsigned int r = v.i + 0x7fffu + ((v.i >> 16) & 1u);
  return (u16)(r >> 16);
}
__device__ __forceinline__ unsigned int pack2bf(float a, float b) {
  union { float f; unsigned int u; } x, y; x.f = a; y.f = b;
  return ((x.u + 0x8000u) >> 16) | ((y.u + 0x8000u) & 0xffff0000u);
}

// ---------------- utility kernels ----------------
__global__ void zero_f32(float* __restrict__ p, long n) {
  long i = ((long)blockIdx.x * blockDim.x + threadIdx.x) * 4;
  if (i >= n) return;
  *(float4*)(p + i) = make_float4(0.f, 0.f, 0.f, 0.f);
}

__global__ void cvt_f32_bf16(const float* __restrict__ in, u16* __restrict__ out, long n) {
  long i = ((long)blockIdx.x * blockDim.x + threadIdx.x) * 4;
  if (i >= n) return;
  float4 v = *(const float4*)(in + i);
  u16 o[4] = { f2bf(v.x), f2bf(v.y), f2bf(v.z), f2bf(v.w) };
  *(uint2*)(out + i) = *(const uint2*)o;
}

__global__ void transpose_f32_bf16(const float* __restrict__ in, u16* __restrict__ out,
                                   int R, int C) {
  __shared__ float tile[32][33];
  int tx = threadIdx.x & 31, ty = threadIdx.x >> 5;       // 32 x 8
  int r0 = blockIdx.y * 32, c0 = blockIdx.x * 32;
#pragma unroll
  for (int k = 0; k < 4; ++k)
    tile[ty + 8 * k][tx] = in[(size_t)(r0 + ty + 8 * k) * C + c0 + tx];
  __syncthreads();
#pragma unroll
  for (int k = 0; k < 4; ++k)
    out[(size_t)(c0 + ty + 8 * k) * R + r0 + tx] = f2bf(tile[tx][ty + 8 * k]);
}

// ---------------- GEMM: C[M,N] = A[M,K](bf16, row stride lda) * B[N,K](bf16)^T + bias ----
typedef __attribute__((ext_vector_type(8))) short s16x8;
typedef __attribute__((ext_vector_type(4))) float fx4;
typedef __attribute__((address_space(1))) unsigned int as1u;
typedef __attribute__((address_space(3))) unsigned int as3u;

__device__ __forceinline__ void gll16(const void* g, void* l) {
  __builtin_amdgcn_global_load_lds((as1u*)g, (as3u*)l, 16, 0, 0);
}

// XCD-partition swizzle: xcd = flat % 8. Row-blocks partitioned by mb%8==xcd,
// column-outer within an XCD so 16 consecutive same-XCD blocks share a B-strip.
__device__ __forceinline__ void swizzle_mn(int MB, int NB, int* mb, int* nb) {
  int flat = blockIdx.y * NB + blockIdx.x;
  if ((MB & 7) == 0) {
    int xcd = flat & 7;
    int j = flat >> 3;
    int rpx = MB >> 3;
    *nb = j / rpx;
    int rowin = j - *nb * rpx;
    *mb = (rowin << 3) | xcd;
  } else {
    *mb = blockIdx.y; *nb = blockIdx.x;
  }
}

template <int RELU, int OUTBF16>
__global__ __launch_bounds__(256, 3) void gemm_bt(const u16* A, int lda,
                                                  const u16* Bm,
                                                  const float* __restrict__ bias,
                                                  void* Cp,
                                                  int M, int N, int K) {
  __shared__ __attribute__((aligned(16))) u16 As[128 * 32];
  __shared__ __attribute__((aligned(16))) u16 Bs[128 * 32];
  int tid = threadIdx.x;
  int lane = tid & 63, wid = tid >> 6;
  int mb, nb;
  swizzle_mn(gridDim.y, gridDim.x, &mb, &nb);
  int m0 = mb * 128, n0 = nb * 128;
  int wm = (wid >> 1) * 64, wn = (wid & 1) * 64;
  int lm = lane & 15, quad = lane >> 4;

  fx4 acc[4][4] = {};

  const u16* Ag = A + (size_t)m0 * lda;
  const u16* Bg = Bm + (size_t)n0 * K;

  for (int k0 = 0; k0 < K; k0 += 32) {
#pragma unroll
    for (int it = 0; it < 2; ++it) {
      int sb = wid * 64 + it * 256;   // wave-uniform seg base
      int s = sb + lane;
      int row = s >> 2, ks = s & 3;
      gll16(Ag + (size_t)row * lda + k0 + ks * 8, (char*)As + (size_t)sb * 16);
      gll16(Bg + (size_t)row * K + k0 + ks * 8, (char*)Bs + (size_t)sb * 16);
    }
    __syncthreads();
    s16x8 af[4], bfr[4];
#pragma unroll
    for (int t = 0; t < 4; ++t) {
      af[t]  = *(const s16x8*)(As + (wm + t * 16 + lm) * 32 + quad * 8);
      bfr[t] = *(const s16x8*)(Bs + (wn + t * 16 + lm) * 32 + quad * 8);
    }
#pragma unroll
    for (int mt = 0; mt < 4; ++mt)
#pragma unroll
      for (int nt = 0; nt < 4; ++nt)
        acc[mt][nt] = __builtin_amdgcn_mfma_f32_16x16x32_bf16(af[mt], bfr[nt], acc[mt][nt], 0, 0, 0);
    __syncthreads();
  }

  float* Cf = (float*)Cp;
  u16* Ch = (u16*)Cp;
#pragma unroll
  for (int mt = 0; mt < 4; ++mt) {
#pragma unroll
    for (int nt = 0; nt < 4; ++nt) {
      int col = n0 + wn + nt * 16 + lm;
      float bv = bias[col];
#pragma unroll
      for (int r = 0; r < 4; ++r) {
        int rowg = m0 + wm + mt * 16 + quad * 4 + r;
        float v = acc[mt][nt][r] + bv;
        if (RELU) v = v > 0.f ? v : 0.f;
        if (OUTBF16) Ch[(size_t)rowg * N + col] = f2bf(v);
        else         Cf[(size_t)rowg * N + col] = v;
      }
    }
  }
}

// split-K variant: grid.z = slices; partials accumulated with f32 HW atomics
// into a pre-zeroed C. No bias (folded into the consumer).
__global__ __launch_bounds__(256, 3) void gemm_bt_sk(const u16* A, int lda,
                                                     const u16* Bm,
                                                     float* Cf,
                                                     int M, int N, int K) {
  __shared__ __attribute__((aligned(16))) u16 As[128 * 32];
  __shared__ __attribute__((aligned(16))) u16 Bs[128 * 32];
  int tid = threadIdx.x;
  int lane = tid & 63, wid = tid >> 6;
  int mb, nb;
  swizzle_mn(gridDim.y, gridDim.x, &mb, &nb);
  int m0 = mb * 128, n0 = nb * 128;
  int wm = (wid >> 1) * 64, wn = (wid & 1) * 64;
  int lm = lane & 15, quad = lane >> 4;

  int ksl = K / gridDim.z;
  int kbeg = blockIdx.z * ksl, kend = kbeg + ksl;

  fx4 acc[4][4] = {};

  const u16* Ag = A + (size_t)m0 * lda;
  const u16* Bg = Bm + (size_t)n0 * K;

  for (int k0 = kbeg; k0 < kend; k0 += 32) {
#pragma unroll
    for (int it = 0; it < 2; ++it) {
      int sb = wid * 64 + it * 256;
      int s = sb + lane;
      int row = s >> 2, ks = s & 3;
      gll16(Ag + (size_t)row * lda + k0 + ks * 8, (char*)As + (size_t)sb * 16);
      gll16(Bg + (size_t)row * K + k0 + ks * 8, (char*)Bs + (size_t)sb * 16);
    }
    __syncthreads();
    s16x8 af[4], bfr[4];
#pragma unroll
    for (int t = 0; t < 4; ++t) {
      af[t]  = *(const s16x8*)(As + (wm + t * 16 + lm) * 32 + quad * 8);
      bfr[t] = *(const s16x8*)(Bs + (wn + t * 16 + lm) * 32 + quad * 8);
    }
#pragma unroll
    for (int mt = 0; mt < 4; ++mt)
#pragma unroll
      for (int nt = 0; nt < 4; ++nt)
        acc[mt][nt] = __builtin_amdgcn_mfma_f32_16x16x32_bf16(af[mt], bfr[nt], acc[mt][nt], 0, 0, 0);
    __syncthreads();
  }

#pragma unroll
  for (int mt = 0; mt < 4; ++mt) {
#pragma unroll
    for (int nt = 0; nt < 4; ++nt) {
      int col = n0 + wn + nt * 16 + lm;
#pragma unroll
      for (int r = 0; r < 4; ++r) {
        int rowg = m0 + wm + mt * 16 + quad * 4 + r;
        unsafeAtomicAdd(Cf + (size_t)rowg * N + col, acc[mt][nt][r]);
      }
    }
  }
}

// ---------------- MFMA flash attention ----------------
#define PADK 72
#define PADV 136
#define PADP 40
#define PADO 72

__global__ __launch_bounds__(256, 2) void attn_mfma(u16* qkv) {
  __shared__ __attribute__((aligned(16))) u16 lds[38400];   // 76.8 KB
  u16* Klds  = lds;                    // 128 x PADK = 9216
  u16* Vtlds = lds + 9216;             // 64 x PADV  = 8704

  int bid = blockIdx.x;
  int h = bid & (Hh - 1);
  int c = (bid >> 4) & (NC - 1);
  int b = bid >> 8;
  int tid = threadIdx.x, lane = tid & 63, w = tid >> 6;
  int lm = lane & 15, quad = lane >> 4;
  u16* Pw = lds + 17920 + w * 5120;

  size_t rowbase = (size_t)b * Lseq;

  s16x8 qf[4][2];
#pragma unroll
  for (int nt = 0; nt < 4; ++nt)
#pragma unroll
    for (int ks = 0; ks < 2; ++ks) {
      int qtok = c * Wc + w * 64 + nt * 16 + lm;
      qf[nt][ks] = *(const s16x8*)(qkv + (rowbase + qtok) * 3072 + h * 64 + ks * 32 + quad * 8);
    }

  fx4 acc_o[4][4] = {};
  float lsum[4] = {0.f, 0.f, 0.f, 0.f};

  int nph = (c > 0) ? 4 : 2;
  int t0  = (c > 0) ? (c - 1) * Wc : 0;

  for (int ph = 0; ph < nph; ++ph) {
    int kt0 = t0 + ph * 128;
    __syncthreads();

#pragma unroll
    for (int it = 0; it < 4; ++it) {
      int s = tid + it * 256;
      int row = s >> 3, off = (s & 7) * 8;
      uint4 kv = *(const uint4*)(qkv + (rowbase + kt0 + row) * 3072 + 1024 + h * 64 + off);
      *(uint4*)(Klds + row * PADK + off) = kv;
    }
    {
      int d = lane;
      int kb = w * 32;
      u16 tmp[32];
#pragma unroll
      for (int i = 0; i < 32; ++i)
        tmp[i] = qkv[(rowbase + kt0 + kb + i) * 3072 + 2048 + h * 64 + d];
#pragma unroll
      for (int i = 0; i < 4; ++i)
        *(uint4*)(Vtlds + d * PADV + kb + i * 8) = *(const uint4*)(tmp + i * 8);
    }
    __syncthreads();

#pragma unroll
    for (int kt = 0; kt < 4; ++kt) {
      u16* Pb = Pw + (kt & 1) * 2560;
      fx4 sa[2][4] = {};
#pragma unroll
      for (int ks = 0; ks < 2; ++ks) {
        s16x8 kf0 = *(const s16x8*)(Klds + (kt * 32 + lm) * PADK + ks * 32 + quad * 8);
        s16x8 kf1 = *(const s16x8*)(Klds + (kt * 32 + 16 + lm) * PADK + ks * 32 + quad * 8);
#pragma unroll
        for (int nt = 0; nt < 4; ++nt) {
          sa[0][nt] = __builtin_amdgcn_mfma_f32_16x16x32_bf16(kf0, qf[nt][ks], sa[0][nt], 0, 0, 0);
          sa[1][nt] = __builtin_amdgcn_mfma_f32_16x16x32_bf16(kf1, qf[nt][ks], sa[1][nt], 0, 0, 0);
        }
      }
#pragma unroll
      for (int mt = 0; mt < 2; ++mt)
#pragma unroll
        for (int nt = 0; nt < 4; ++nt) {
          float e0 = __expf(sa[mt][nt][0] * 0.125f);
          float e1 = __expf(sa[mt][nt][1] * 0.125f);
          float e2 = __expf(sa[mt][nt][2] * 0.125f);
          float e3 = __expf(sa[mt][nt][3] * 0.125f);
          lsum[nt] += (e0 + e1) + (e2 + e3);
          uint2 pk; pk.x = pack2bf(e0, e1); pk.y = pack2bf(e2, e3);
          *(uint2*)(Pb + (nt * 16 + lm) * PADP + mt * 16 + quad * 4) = pk;
        }
#pragma unroll
      for (int mt = 0; mt < 4; ++mt) {
        s16x8 vf = *(const s16x8*)(Vtlds + (mt * 16 + lm) * PADV + kt * 32 + quad * 8);
#pragma unroll
        for (int nt = 0; nt < 4; ++nt) {
          s16x8 pf = *(const s16x8*)(Pb + (nt * 16 + lm) * PADP + quad * 8);
          acc_o[mt][nt] = __builtin_amdgcn_mfma_f32_16x16x32_bf16(vf, pf, acc_o[mt][nt], 0, 0, 0);
        }
      }
    }
  }

#pragma unroll
  for (int nt = 0; nt < 4; ++nt) {
    float v = lsum[nt];
    v += __shfl_xor(v, 16, 64);
    v += __shfl_xor(v, 32, 64);
    lsum[nt] = 1.f / v;
  }

  __syncthreads();
  u16* Obuf = lds;
#pragma unroll
  for (int mt = 0; mt < 4; ++mt)
#pragma unroll
    for (int nt = 0; nt < 4; ++nt) {
      float inv = lsum[nt];
      uint2 pk;
      pk.x = pack2bf(acc_o[mt][nt][0] * inv, acc_o[mt][nt][1] * inv);
      pk.y = pack2bf(acc_o[mt][nt][2] * inv, acc_o[mt][nt][3] * inv);
      int q = nt * 16 + lm;
      *(uint2*)(Obuf + (w * 64 + q) * PADO + mt * 16 + quad * 4) = pk;
    }
  __syncthreads();
#pragma unroll
  for (int it = 0; it < 8; ++it) {
    int s = tid + it * 256;
    int row = s >> 3, chunk = s & 7;
    uint4 v = *(const uint4*)(Obuf + row * PADO + chunk * 8);
    *(uint4*)(qkv + (rowbase + c * Wc + row) * 3072 + h * 64 + chunk * 8) = v;
  }
}

// ---------------- layernorm variants ----------------
__device__ __forceinline__ void ln_core(float sx, float sy, float sz, float sw,
                                        const float* gamma, const float* beta, int tid,
                                        float* red, float4* outv) {
  float part = sx + sy + sz + sw;
#pragma unroll
  for (int off = 32; off > 0; off >>= 1) part += __shfl_down(part, off, 64);
  if ((tid & 63) == 0) red[tid >> 6] = part;
  __syncthreads();
  float mean = (red[0] + red[1] + red[2] + red[3]) * (1.f / 1024.f);
  __syncthreads();

  float dx = sx - mean, dy = sy - mean, dz = sz - mean, dw = sw - mean;
  float sq = dx * dx + dy * dy + dz * dz + dw * dw;
#pragma unroll
  for (int off = 32; off > 0; off >>= 1) sq += __shfl_down(sq, off, 64);
  if ((tid & 63) == 0) red[tid >> 6] = sq;
  __syncthreads();
  float var = (red[0] + red[1] + red[2] + red[3]) * (1.f / 1024.f);
  float rs = rsqrtf(var + 1e-6f);

  float4 g = *(const float4*)(gamma + tid * 4);
  float4 be = *(const float4*)(beta + tid * 4);
  outv->x = g.x * dx * rs + be.x;
  outv->y = g.y * dy * rs + be.y;
  outv->z = g.z * dz * rs + be.z;
  outv->w = g.w * dw * rs + be.w;
}

__global__ __launch_bounds__(256) void ln1_kernel(const float* __restrict__ r,
                                                  const float* __restrict__ dl,
                                                  const float* __restrict__ gamma,
                                                  const float* __restrict__ beta,
                                                  u16* __restrict__ outh) {
  __shared__ float red[4];
  int row = blockIdx.x, tid = threadIdx.x;
  size_t base = (size_t)row * Dm;
  float4 rv = *(const float4*)(r + base + tid * 4);
  float4 dv = *(const float4*)(dl + base + tid * 4);
  float4 o;
  ln_core(rv.x + dv.x, rv.y + dv.y, rv.z + dv.z, rv.w + dv.w, gamma, beta, tid, red, &o);
  u16 u[4] = { f2bf(o.x), f2bf(o.y), f2bf(o.z), f2bf(o.w) };
  *(uint2*)(outh + base + tid * 4) = *(const uint2*)u;
}

// LN2: sum = bf16 x1 + f32 y2 (split-K partials) + colbias (bf2); -> f32 out (in-place ok)
__global__ __launch_bounds__(256) void ln2_kernel(const u16* __restrict__ r,
                                                  const float* dl,
                                                  const float* __restrict__ colbias,
                                                  const float* __restrict__ gamma,
                                                  const float* __restrict__ beta,
                                                  float* outf) {
  __shared__ float red[4];
  int row = blockIdx.x, tid = threadIdx.x;
  size_t base = (size_t)row * Dm;
  uint2 ru = *(const uint2*)(r + base + tid * 4);
  const u16* pu = (const u16*)&ru;
  float4 dv = *(const float4*)(dl + base + tid * 4);
  float4 bb = *(const float4*)(colbias + tid * 4);
  float4 o;
  ln_core(bf2f(pu[0]) + dv.x + bb.x, bf2f(pu[1]) + dv.y + bb.y,
          bf2f(pu[2]) + dv.z + bb.z, bf2f(pu[3]) + dv.w + bb.w,
          gamma, beta, tid, red, &o);
  *(float4*)(outf + base + tid * 4) = o;
}

// ---------------- launch ----------------
extern "C" void kernel_launch(void* const* d_in, const int* in_sizes, int n_in,
                              void* d_out, int out_size, void* d_ws, size_t ws_size,
                              hipStream_t stream) {
  const float* x         = (const float*)d_in[0];
  const float* in_proj_w = (const float*)d_in[1];
  const float* in_proj_b = (const float*)d_in[2];
  const float* out_w     = (const float*)d_in[3];
  const float* out_b     = (const float*)d_in[4];
  const float* gamma1    = (const float*)d_in[5];
  const float* beta1     = (const float*)d_in[6];
  const float* w1        = (const float*)d_in[7];
  const float* bf1       = (const float*)d_in[8];
  const float* w2        = (const float*)d_in[9];
  const float* bf2       = (const float*)d_in[10];
  const float* gamma2    = (const float*)d_in[11];
  const float* beta2     = (const float*)d_in[12];
  float* out = (float*)d_out;

  char* ws = (char*)d_ws;
  size_t off = 0;
  auto alloc = [&](size_t bytes) -> char* {
    char* p = ws + off;
    off += (bytes + 255) & ~(size_t)255;
    return p;
  };
  u16* wqkvh = (u16*)alloc((size_t)3 * Dm * Dm * 2);
  u16* owh   = (u16*)alloc((size_t)Dm * Dm * 2);
  u16* w1th  = (u16*)alloc((size_t)FFd * Dm * 2);
  u16* w2th  = (u16*)alloc((size_t)Dm * FFd * 2);
  u16* big   = (u16*)alloc((size_t)NTOK * FFd * 2);
  u16* x1h   = (u16*)alloc((size_t)NTOK * Dm * 2);
  u16* qkvh = big;
  u16* hh   = big;
  u16* xh   = (u16*)d_out;
  float* attnf = out;
  float* y2f   = out;

  cvt_f32_bf16<<<(long)NTOK * Dm / 1024, 256, 0, stream>>>(x, xh, (long)NTOK * Dm);
  cvt_f32_bf16<<<(long)3 * Dm * Dm / 1024, 256, 0, stream>>>(in_proj_w, wqkvh, (long)3 * Dm * Dm);
  cvt_f32_bf16<<<(long)Dm * Dm / 1024, 256, 0, stream>>>(out_w, owh, (long)Dm * Dm);
  transpose_f32_bf16<<<dim3(FFd / 32, Dm / 32), 256, 0, stream>>>(w1, w1th, Dm, FFd);
  transpose_f32_bf16<<<dim3(Dm / 32, FFd / 32), 256, 0, stream>>>(w2, w2th, FFd, Dm);

  gemm_bt<0, 1><<<dim3(3 * Dm / 128, NTOK / 128), 256, 0, stream>>>(
      xh, Dm, wqkvh, in_proj_b, qkvh, NTOK, 3 * Dm, Dm);

  attn_mfma<<<Bsz * NC * Hh, 256, 0, stream>>>(qkvh);

  gemm_bt<0, 0><<<dim3(Dm / 128, NTOK / 128), 256, 0, stream>>>(
      qkvh, 3 * Dm, owh, out_b, attnf, NTOK, Dm, Dm);

  ln1_kernel<<<NTOK, 256, 0, stream>>>(x, attnf, gamma1, beta1, x1h);

  gemm_bt<1, 1><<<dim3(FFd / 128, NTOK / 128), 256, 0, stream>>>(
      x1h, Dm, w1th, bf1, hh, NTOK, FFd, Dm);

  // y2 = h @ w2 (split-K=2, atomic partials into zeroed d_out; bf2 folded into LN2)
  zero_f32<<<(long)NTOK * Dm / 1024, 256, 0, stream>>>(y2f, (long)NTOK * Dm);
  gemm_bt_sk<<<dim3(Dm / 128, NTOK / 128, 2), 256, 0, stream>>>(
      hh, FFd, w2th, y2f, NTOK, Dm, FFd);

  ln2_kernel<<<NTOK, 256, 0, stream>>>(x1h, y2f, bf2, gamma2, beta2, out);
}